// Round 6
// baseline (270.885 us; speedup 1.0000x reference)
//
#include <hip/hip_runtime.h>
#include <stdint.h>

#pragma clang fp contract(off)

// ---------------------------------------------------------------------------
// Binary ConvBlock, matched to the fp32 numpy reference (round-5 semantics,
// bit-exact):
//   - stage 1: conv1x1(x, sgn w11): SEQUENTIAL fp32 chain over ci=0..255
//     ascending. Implemented as v_fma_f32(acc, +-1.0f, x) which is
//     bit-identical to fl(acc +- x). fp32 BN threshold.
//   - stages 2-4: exact-integer popcount convs, fp32 BN threshold:
//       inv = g/sqrt(v+1e-4f); beta = b - m*inv; val = y*inv + beta
//     (each op correctly rounded fp32, no contraction).
// conv3x3 split into interior (no boundary masks, 93% of px) and boundary.
// B=16, Cin=256, down=64, up=256, H=W=56. 3136 = 56*56 = 49*64.
// ---------------------------------------------------------------------------

#define HW_   3136          // 56*56

// workspace layout (bytes, 16-aligned)
#define OFF_W31B   2048      // 2304 u64 ([co][tap])
#define OFF_W12B   20480     // 256 u64  ([co][k])
#define OFF_W32B   22528     // 2304 u64
#define OFF_IV11   40960     // 64 float2
#define OFF_IV31   41472     // 256 float2
#define OFF_IV12   43520     // 64 float2
#define OFF_IV32   44032     // 256 float2
#define OFF_A1     46080     // 50176 u64
#define OFF_H      447488    // 50176*4 u64
#define OFF_A2     2053120   // 50176 u64
#define OFF_S      2454528   // 50176*4 u64
#define OFF_SGNT   4060160   // 16384 f32 (+-1.0 sign table) = 65536 B

__device__ inline float2 mk_ivbt(float g, float b, float m, float v) {
    float inv  = __fdiv_rn(g, __fsqrt_rn(__fadd_rn(v, 1e-4f)));
    float beta = __fsub_rn(b, __fmul_rn(m, inv));
    return make_float2(inv, beta);
}

// --------------------------- K0: pack weights ------------------------------
__global__ __launch_bounds__(256) void k0_prep(
    const float* __restrict__ w31, const float* __restrict__ w12,
    const float* __restrict__ w32,
    const float* __restrict__ g11, const float* __restrict__ b11,
    const float* __restrict__ m11, const float* __restrict__ v11,
    const float* __restrict__ g31, const float* __restrict__ b31,
    const float* __restrict__ m31, const float* __restrict__ v31,
    const float* __restrict__ g12, const float* __restrict__ b12,
    const float* __restrict__ m12, const float* __restrict__ v12,
    const float* __restrict__ g32, const float* __restrict__ b32,
    const float* __restrict__ m32, const float* __restrict__ v32,
    uint64_t* __restrict__ W31b, uint64_t* __restrict__ W12b,
    uint64_t* __restrict__ W32b,
    float2* __restrict__ iv11, float2* __restrict__ iv31,
    float2* __restrict__ iv12, float2* __restrict__ iv32)
{
    int t = blockIdx.x * 256 + threadIdx.x;
    if (t < 2304) {                      // W31b[co*9+tap]: bit ci
        int co = t / 9, tap = t % 9;
        uint64_t bits = 0;
        for (int ci = 0; ci < 64; ++ci)
            bits |= (uint64_t)(w31[(co * 64 + ci) * 9 + tap] >= 0.f) << ci;
        W31b[t] = bits;
    } else if (t < 2560) {               // W12b[co*4+k]: bit ci'
        int i = t - 2304, co = i >> 2, k = i & 3;
        uint64_t bits = 0;
        for (int ci = 0; ci < 64; ++ci)
            bits |= (uint64_t)(w12[co * 256 + k * 64 + ci] >= 0.f) << ci;
        W12b[i] = bits;
    } else if (t < 4864) {               // W32b
        int i = t - 2560, co = i / 9, tap = i % 9;
        uint64_t bits = 0;
        for (int ci = 0; ci < 64; ++ci)
            bits |= (uint64_t)(w32[(co * 64 + ci) * 9 + tap] >= 0.f) << ci;
        W32b[i] = bits;
    } else if (t < 5504) {               // BN (inv, beta) in fp32, np op order
        int i = t - 4864;
        if (i < 64)        iv11[i]       = mk_ivbt(g11[i],       b11[i],       m11[i],       v11[i]);
        else if (i < 320)  iv31[i - 64]  = mk_ivbt(g31[i - 64],  b31[i - 64],  m31[i - 64],  v31[i - 64]);
        else if (i < 384)  iv12[i - 320] = mk_ivbt(g12[i - 320], b12[i - 320], m12[i - 320], v12[i - 320]);
        else               iv32[i - 384] = mk_ivbt(g32[i - 384], b32[i - 384], m32[i - 384], v32[i - 384]);
    }
}

// ---------------- K0b: +-1.0f sign table for stage-1 weights ---------------
// layout: sgnT[(ci*4 + g)*16 + jj] = sign(w11[g*16+jj][ci]) as +-1.0f
// (64 B per (ci, g) -> s_load_dwordx16-friendly)
__global__ __launch_bounds__(256) void k0b_sgn(
    const float* __restrict__ w11, float* __restrict__ sgnT)
{
    int t = blockIdx.x * 256 + threadIdx.x;   // < 16384
    int ci = t >> 6, j = t & 63;
    sgnT[(ci * 4 + (j >> 4)) * 16 + (j & 15)] =
        (w11[j * 256 + ci] >= 0.f) ? 1.0f : -1.0f;
}

// ------------- K1: fp32 SEQUENTIAL conv1x1 (x * sgn w11) + sign ------------
// grid 784 (= 16 b * 49 pixel-chunks), block 256 = 64 pixels (l) x 4 groups.
// Wave g owns output channels [16g,16g+16). Each accumulator is one
// sequential fp32 chain over ci = 0..255 ascending via fma(+-1, x, acc).
__global__ __launch_bounds__(256) void k1_conv1(
    const float* __restrict__ x, const float* __restrict__ sgnT,
    const float2* __restrict__ ivbt, uint64_t* __restrict__ A1)
{
    __shared__ float xs[16][64];
    __shared__ unsigned short sh[64][4];

    const int t = threadIdx.x;
    const int l = t & 63;          // pixel within chunk
    const int g = t >> 6;          // wave = channel group 0..3
    const int gu = __builtin_amdgcn_readfirstlane(g);   // SGPR group id
    const int tile = blockIdx.x;   // 784 = 16 * 49
    const int b = tile / 49;
    const int hw0 = (tile % 49) * 64;
    const float* xp = x + (size_t)b * 256 * HW_ + hw0 + l;

    float acc[16];
#pragma unroll
    for (int jj = 0; jj < 16; ++jj) acc[jj] = 0.0f;

    for (int cb = 0; cb < 256; cb += 16) {
#pragma unroll
        for (int k = 0; k < 4; ++k) {
            int c = g * 4 + k;                        // 0..15
            xs[c][l] = xp[(size_t)(cb + c) * HW_];
        }
        __syncthreads();
#pragma unroll
        for (int c = 0; c < 16; ++c) {                // ci = cb + c ascending
            float xv = xs[c][l];
            const float* sp = sgnT + (((cb + c) * 4 + gu) << 4);  // 16 x +-1.0f
#pragma unroll
            for (int jj = 0; jj < 16; ++jj)
                acc[jj] = __builtin_fmaf(sp[jj], xv, acc[jj]);
        }
        __syncthreads();
    }

    unsigned short bits16 = 0;
#pragma unroll
    for (int jj = 0; jj < 16; ++jj) {
        float2 ib = ivbt[g * 16 + jj];
        float val = __fadd_rn(__fmul_rn(acc[jj], ib.x), ib.y);
        bits16 |= (unsigned short)((val >= 0.0f) ? (1u << jj) : 0u);
    }
    sh[l][g] = bits16;
    __syncthreads();
    if (g == 0) {
        uint64_t w0 = (uint64_t)sh[l][0]
                    | ((uint64_t)sh[l][1] << 16)
                    | ((uint64_t)sh[l][2] << 32)
                    | ((uint64_t)sh[l][3] << 48);
        A1[tile * 64 + l] = w0;
    }
}

// -------- conv3x3 INTERIOR (1<=h<=54, 1<=w<=54): no boundary masks ---------
// grid 729 (= 46656 px / 64), block 256 = 64 px (l) x 4 quarters (q).
template <bool MERGE>
__global__ __launch_bounds__(256) void k_conv3_int(
    const uint64_t* __restrict__ A, const uint64_t* __restrict__ Wb,
    const float2* __restrict__ ivbt, const uint64_t* __restrict__ Hin,
    uint64_t* __restrict__ Out)
{
    const int t = threadIdx.x;
    const int l = t & 63;
    const int q = t >> 6;
    const int P = blockIdx.x * 64 + l;       // < 16*2916 = 46656
    const int b = P / 2916;
    const int p = P % 2916;
    const int h = 1 + p / 54, w = 1 + p % 54;
    const int hw = h * 56 + w;
    const uint64_t* Ap = A + b * HW_ + hw;

    uint64_t a0 = Ap[-57], a1 = Ap[-56], a2 = Ap[-55],
             a3 = Ap[-1],  a4 = Ap[0],   a5 = Ap[1],
             a6 = Ap[55],  a7 = Ap[56],  a8 = Ap[57];

    uint64_t bits = 0;
#pragma unroll 4
    for (int jo = 0; jo < 64; ++jo) {
        const uint64_t* wp = Wb + (q * 64 + jo) * 9;
        int s = (int)(__popcll(a0 ^ wp[0]) + __popcll(a1 ^ wp[1]) +
                      __popcll(a2 ^ wp[2]) + __popcll(a3 ^ wp[3]) +
                      __popcll(a4 ^ wp[4]) + __popcll(a5 ^ wp[5]) +
                      __popcll(a6 ^ wp[6]) + __popcll(a7 ^ wp[7]) +
                      __popcll(a8 ^ wp[8]));
        int y = 576 - 2 * s;
        float2 ib = ivbt[q * 64 + jo];
        float val = __fadd_rn(__fmul_rn((float)y, ib.x), ib.y);
        bits |= (uint64_t)(val >= 0.0f) << jo;
    }
    size_t oidx = (size_t)(b * HW_ + hw) * 4 + q;
    if (MERGE) bits |= Hin[oidx];
    Out[oidx] = bits;
}

// ------------- conv3x3 BOUNDARY (220 px/image): masked taps ----------------
// grid 55 (= 16*220/64), block 256 = 64 px (l) x 4 quarters (q).
template <bool MERGE>
__global__ __launch_bounds__(256) void k_conv3_bnd(
    const uint64_t* __restrict__ A, const uint64_t* __restrict__ Wb,
    const float2* __restrict__ ivbt, const uint64_t* __restrict__ Hin,
    uint64_t* __restrict__ Out)
{
    const int t = threadIdx.x;
    const int l = t & 63;
    const int q = t >> 6;
    const int P = blockIdx.x * 64 + l;       // < 16*220 = 3520
    const int b = P / 220;
    const int p = P % 220;
    int h, w;
    if (p < 56)       { h = 0;        w = p;       }
    else if (p < 112) { h = 55;       w = p - 56;  }
    else if (p < 166) { h = p - 111;  w = 0;       }
    else              { h = p - 165;  w = 55;      }
    const int hw = h * 56 + w;
    const uint64_t* Ab = A + b * HW_;

    uint64_t a[9];
    bool v[9];
#pragma unroll
    for (int ky = 0; ky < 3; ++ky)
#pragma unroll
        for (int kx = 0; kx < 3; ++kx) {
            int ih = h + ky - 1, iw = w + kx - 1;
            int tt = ky * 3 + kx;
            bool ok = ((unsigned)ih < 56u) && ((unsigned)iw < 56u);
            v[tt] = ok;
            a[tt] = ok ? Ab[ih * 56 + iw] : 0ull;
        }

    uint64_t bits = 0;
#pragma unroll 4
    for (int jo = 0; jo < 64; ++jo) {
        const uint64_t* wp = Wb + (q * 64 + jo) * 9;
        int y = 0;
#pragma unroll
        for (int tt = 0; tt < 9; ++tt)
            y += v[tt] ? (64 - 2 * (int)__popcll(a[tt] ^ wp[tt])) : 0;
        float2 ib = ivbt[q * 64 + jo];
        float val = __fadd_rn(__fmul_rn((float)y, ib.x), ib.y);
        bits |= (uint64_t)(val >= 0.0f) << jo;
    }
    size_t oidx = (size_t)(b * HW_ + hw) * 4 + q;
    if (MERGE) bits |= Hin[oidx];
    Out[oidx] = bits;
}

// ------------- K3: binary conv1x1 256->64 (bits -> bits) -------------------
__global__ __launch_bounds__(256) void k3_conv1b(
    const uint64_t* __restrict__ H, const uint64_t* __restrict__ W12b,
    const float2* __restrict__ ivbt, uint64_t* __restrict__ A2)
{
    int p = blockIdx.x * 256 + threadIdx.x;   // < 50176
    const uint64_t* hp = H + (size_t)p * 4;
    uint64_t h0 = hp[0], h1 = hp[1], h2 = hp[2], h3 = hp[3];
    uint64_t bits = 0;
#pragma unroll 4
    for (int co = 0; co < 64; ++co) {
        const uint64_t* wp = W12b + co * 4;
        int s = (int)(__popcll(h0 ^ wp[0]) + __popcll(h1 ^ wp[1]) +
                      __popcll(h2 ^ wp[2]) + __popcll(h3 ^ wp[3]));
        int y = 256 - 2 * s;
        float2 ib = ivbt[co];
        float val = __fadd_rn(__fmul_rn((float)y, ib.x), ib.y);
        bits |= (uint64_t)(val >= 0.0f) << co;
    }
    A2[p] = bits;
}

// ------------- K4b: OR-pool 2x2 + write +-1.0f -----------------------------
__global__ __launch_bounds__(256) void k4b_pool(
    const uint64_t* __restrict__ S, float* __restrict__ out)
{
    int o = blockIdx.x * 256 + threadIdx.x;   // < 16*256*28*28 = 3211264
    int ow = o % 28;
    int t = o / 28;
    int oh = t % 28; t /= 28;
    int co = t % 256;
    int b = t / 256;
    int k = co >> 6, j = co & 63;
    const uint64_t* Sp = S + ((size_t)(b * 56 + 2 * oh) * 56 + 2 * ow) * 4 + k;
    uint64_t s = Sp[0] | Sp[4] | Sp[224] | Sp[228];
    out[o] = ((s >> j) & 1) ? 1.0f : -1.0f;
}

// ---------------------------------------------------------------------------
extern "C" void kernel_launch(void* const* d_in, const int* in_sizes, int n_in,
                              void* d_out, int out_size, void* d_ws, size_t ws_size,
                              hipStream_t stream)
{
    const float* x   = (const float*)d_in[0];
    const float* w11 = (const float*)d_in[1];
    const float* w31 = (const float*)d_in[2];
    const float* w12 = (const float*)d_in[3];
    const float* w32 = (const float*)d_in[4];
    const float* g11 = (const float*)d_in[5];
    const float* b11 = (const float*)d_in[6];
    const float* m11 = (const float*)d_in[7];
    const float* v11 = (const float*)d_in[8];
    const float* g31 = (const float*)d_in[9];
    const float* b31 = (const float*)d_in[10];
    const float* m31 = (const float*)d_in[11];
    const float* v31 = (const float*)d_in[12];
    const float* g12 = (const float*)d_in[13];
    const float* b12 = (const float*)d_in[14];
    const float* m12 = (const float*)d_in[15];
    const float* v12 = (const float*)d_in[16];
    const float* g32 = (const float*)d_in[17];
    const float* b32 = (const float*)d_in[18];
    const float* m32 = (const float*)d_in[19];
    const float* v32 = (const float*)d_in[20];

    char* ws = (char*)d_ws;
    uint64_t* W31b = (uint64_t*)(ws + OFF_W31B);
    uint64_t* W12b = (uint64_t*)(ws + OFF_W12B);
    uint64_t* W32b = (uint64_t*)(ws + OFF_W32B);
    float2* iv11 = (float2*)(ws + OFF_IV11);
    float2* iv31 = (float2*)(ws + OFF_IV31);
    float2* iv12 = (float2*)(ws + OFF_IV12);
    float2* iv32 = (float2*)(ws + OFF_IV32);
    uint64_t* A1 = (uint64_t*)(ws + OFF_A1);
    uint64_t* Hb = (uint64_t*)(ws + OFF_H);
    uint64_t* A2 = (uint64_t*)(ws + OFF_A2);
    uint64_t* Sb = (uint64_t*)(ws + OFF_S);
    float*  sgnT = (float*)(ws + OFF_SGNT);

    k0_prep<<<dim3(22), dim3(256), 0, stream>>>(
        w31, w12, w32,
        g11, b11, m11, v11, g31, b31, m31, v31,
        g12, b12, m12, v12, g32, b32, m32, v32,
        W31b, W12b, W32b, iv11, iv31, iv12, iv32);

    k0b_sgn<<<dim3(64), dim3(256), 0, stream>>>(w11, sgnT);

    k1_conv1<<<dim3(784), dim3(256), 0, stream>>>(x, sgnT, iv11, A1);

    k_conv3_int<false><<<dim3(729), dim3(256), 0, stream>>>(A1, W31b, iv31, (const uint64_t*)nullptr, Hb);
    k_conv3_bnd<false><<<dim3(55),  dim3(256), 0, stream>>>(A1, W31b, iv31, (const uint64_t*)nullptr, Hb);

    k3_conv1b<<<dim3(196), dim3(256), 0, stream>>>(Hb, W12b, iv12, A2);

    k_conv3_int<true><<<dim3(729), dim3(256), 0, stream>>>(A2, W32b, iv32, Hb, Sb);
    k_conv3_bnd<true><<<dim3(55),  dim3(256), 0, stream>>>(A2, W32b, iv32, Hb, Sb);

    k4b_pool<<<dim3(12544), dim3(256), 0, stream>>>(Sb, (float*)d_out);
}

// Round 7
// 211.952 us; speedup vs baseline: 1.2781x; 1.2781x over previous
//
#include <hip/hip_runtime.h>
#include <stdint.h>

#pragma clang fp contract(off)

// ---------------------------------------------------------------------------
// Binary ConvBlock, bit-exact to the fp32 numpy reference (validated r5/r6):
//   - stage 1: conv1x1(x, sgn w11): SEQUENTIAL fp32 chain over ci=0..255
//     ascending via fma(+-1.0f, x, acc) == fl(acc +- x). fp32 BN threshold.
//   - stages 2-4: exact-integer popcount convs, fp32 BN threshold:
//       inv = g/sqrt(v+1e-4f); beta = b - m*inv; val = y*inv + beta.
// Structure: k1 barrier-free (wave = 32ch x 64px); conv3 in ballot form
// (lane = co, weights in VGPRs, taps via zero-padded LDS tile, output word
// assembled by __ballot). H/S planar [quarter][px] for coalescing.
// B=16, Cin=256, down=64, up=256, H=W=56. 3136 = 56*56 = 49*64.
// ---------------------------------------------------------------------------

#define HW_   3136          // 56*56
#define NPIX  50176         // 16*3136

// workspace layout (bytes)
#define OFF_W31B   0         // 2304 u64 ([co][tap])
#define OFF_W12B   18432     // 256 u64  ([co][k])
#define OFF_W32B   20480     // 2304 u64
#define OFF_IV11   38912     // 64 float2
#define OFF_IV31   39424     // 256 float2
#define OFF_IV12   41472     // 64 float2
#define OFF_IV32   41984     // 256 float2
#define OFF_SGNT   44032     // 16384 f32 (+-1.0f, [ci][j])
#define OFF_A1     109568    // 50176 u64 (bit j = ch j)
#define OFF_A2     510976    // 50176 u64
#define OFF_H      912384    // 4 planes x 50176 u64 (bit = co within quarter)
#define OFF_S      2518016   // 4 planes x 50176 u64

__device__ inline float2 mk_ivbt(float g, float b, float m, float v) {
    float inv  = __fdiv_rn(g, __fsqrt_rn(__fadd_rn(v, 1e-4f)));
    float beta = __fsub_rn(b, __fmul_rn(m, inv));
    return make_float2(inv, beta);
}

// --------------------------- K0: pack weights ------------------------------
__global__ __launch_bounds__(256) void k0_prep(
    const float* __restrict__ w31, const float* __restrict__ w12,
    const float* __restrict__ w32,
    const float* __restrict__ g11, const float* __restrict__ b11,
    const float* __restrict__ m11, const float* __restrict__ v11,
    const float* __restrict__ g31, const float* __restrict__ b31,
    const float* __restrict__ m31, const float* __restrict__ v31,
    const float* __restrict__ g12, const float* __restrict__ b12,
    const float* __restrict__ m12, const float* __restrict__ v12,
    const float* __restrict__ g32, const float* __restrict__ b32,
    const float* __restrict__ m32, const float* __restrict__ v32,
    uint64_t* __restrict__ W31b, uint64_t* __restrict__ W12b,
    uint64_t* __restrict__ W32b,
    float2* __restrict__ iv11, float2* __restrict__ iv31,
    float2* __restrict__ iv12, float2* __restrict__ iv32)
{
    int t = blockIdx.x * 256 + threadIdx.x;
    if (t < 2304) {                      // W31b[co*9+tap]: bit ci
        int co = t / 9, tap = t % 9;
        uint64_t bits = 0;
        for (int ci = 0; ci < 64; ++ci)
            bits |= (uint64_t)(w31[(co * 64 + ci) * 9 + tap] >= 0.f) << ci;
        W31b[t] = bits;
    } else if (t < 2560) {               // W12b[co*4+k]: bit ci'
        int i = t - 2304, co = i >> 2, k = i & 3;
        uint64_t bits = 0;
        for (int ci = 0; ci < 64; ++ci)
            bits |= (uint64_t)(w12[co * 256 + k * 64 + ci] >= 0.f) << ci;
        W12b[i] = bits;
    } else if (t < 4864) {               // W32b
        int i = t - 2560, co = i / 9, tap = i % 9;
        uint64_t bits = 0;
        for (int ci = 0; ci < 64; ++ci)
            bits |= (uint64_t)(w32[(co * 64 + ci) * 9 + tap] >= 0.f) << ci;
        W32b[i] = bits;
    } else if (t < 5504) {               // BN (inv, beta) in fp32, np op order
        int i = t - 4864;
        if (i < 64)        iv11[i]       = mk_ivbt(g11[i],       b11[i],       m11[i],       v11[i]);
        else if (i < 320)  iv31[i - 64]  = mk_ivbt(g31[i - 64],  b31[i - 64],  m31[i - 64],  v31[i - 64]);
        else if (i < 384)  iv12[i - 320] = mk_ivbt(g12[i - 320], b12[i - 320], m12[i - 320], v12[i - 320]);
        else               iv32[i - 384] = mk_ivbt(g32[i - 384], b32[i - 384], m32[i - 384], v32[i - 384]);
    }
}

// ---------------- K0b: +-1.0f sign table, layout [ci][j] -------------------
__global__ __launch_bounds__(256) void k0b_sgn(
    const float* __restrict__ w11, float* __restrict__ sgnT)
{
    int t = blockIdx.x * 256 + threadIdx.x;   // < 16384; t = j*256 + ci
    int j = t >> 8, ci = t & 255;
    sgnT[ci * 64 + j] = (w11[t] >= 0.f) ? 1.0f : -1.0f;
}

// ------------- K1: fp32 SEQUENTIAL conv1x1 (x * sgn w11) + sign ------------
// grid 392, block 256 = 4 waves. Wave handles (px-chunk of 64, ch-half of 32).
// Barrier-free: lane = pixel (coalesced x loads), signs via uniform s_load.
__global__ __launch_bounds__(256) void k1_conv1(
    const float* __restrict__ x, const float* __restrict__ sgnT,
    const float2* __restrict__ ivbt, uint32_t* __restrict__ A1)
{
    const int l = threadIdx.x & 63;
    const int wv = threadIdx.x >> 6;
    const int chunk = blockIdx.x * 2 + (wv >> 1);   // 0..783
    const int half = wv & 1;
    const int b = chunk / 49;
    const int hw0 = (chunk % 49) * 64;
    const float* xp = x + (size_t)b * 256 * HW_ + hw0 + l;
    const float* sg = sgnT + half * 32;

    float acc[32];
#pragma unroll
    for (int j = 0; j < 32; ++j) acc[j] = 0.0f;

    for (int ci = 0; ci < 256; ci += 4) {           // ci ascending
        float xv0 = xp[(size_t)(ci + 0) * HW_];
        float xv1 = xp[(size_t)(ci + 1) * HW_];
        float xv2 = xp[(size_t)(ci + 2) * HW_];
        float xv3 = xp[(size_t)(ci + 3) * HW_];
        const float* s0 = sg + (ci + 0) * 64;
        const float* s1 = sg + (ci + 1) * 64;
        const float* s2 = sg + (ci + 2) * 64;
        const float* s3 = sg + (ci + 3) * 64;
#pragma unroll
        for (int j = 0; j < 32; ++j) acc[j] = __builtin_fmaf(s0[j], xv0, acc[j]);
#pragma unroll
        for (int j = 0; j < 32; ++j) acc[j] = __builtin_fmaf(s1[j], xv1, acc[j]);
#pragma unroll
        for (int j = 0; j < 32; ++j) acc[j] = __builtin_fmaf(s2[j], xv2, acc[j]);
#pragma unroll
        for (int j = 0; j < 32; ++j) acc[j] = __builtin_fmaf(s3[j], xv3, acc[j]);
    }

    unsigned bits = 0;
#pragma unroll
    for (int j = 0; j < 32; ++j) {
        float2 ib = ivbt[half * 32 + j];
        float val = __fadd_rn(__fmul_rn(acc[j], ib.x), ib.y);
        bits |= (val >= 0.0f) ? (1u << j) : 0u;
    }
    A1[(size_t)(b * HW_ + hw0 + l) * 2 + half] = bits;
}

// --------- conv3x3 ballot form: 64ch bits -> 256ch bits (planar out) -------
// grid 784, block 256 = 4 waves; wave = co-quarter, lane = co within quarter.
// Weights in VGPRs; taps from zero-padded LDS tile [4][58]; uniform px loop;
// output word assembled by __ballot (bit = lane = co). MERGE ORs Hin plane.
template <bool MERGE>
__global__ __launch_bounds__(256) void k_conv3b(
    const uint64_t* __restrict__ A, const uint64_t* __restrict__ Wb,
    const float2* __restrict__ ivbt, const uint64_t* __restrict__ Hin,
    uint64_t* __restrict__ Out)
{
    __shared__ uint64_t tile[4 * 58];
    const int l = threadIdx.x & 63;
    const int wv = threadIdx.x >> 6;
    const int chunk = blockIdx.x;            // 0..783
    const int b = chunk / 49;
    const int hw0 = (chunk % 49) * 64;
    const int r0 = hw0 / 56;
    const int o  = hw0 % 56;                 // 0..48 (chunk spans rows r0,r0+1)
    const int rfirst = r0 - 1;

    // stage zero-padded tile rows rfirst..rfirst+3, cols -1..56
    {
        int idx = threadIdx.x;
        if (idx < 4 * 58) {
            int rr = idx / 58, cc = idx % 58;
            int gh = rfirst + rr, gw = cc - 1;
            uint64_t v = 0;
            if ((unsigned)gh < 56u && (unsigned)gw < 56u)
                v = A[b * HW_ + gh * 56 + gw];
            tile[idx] = v;
        }
    }

    const int co = wv * 64 + l;
    uint64_t wp[9];
    int c64[9];
#pragma unroll
    for (int t = 0; t < 9; ++t) {
        wp[t] = Wb[co * 9 + t];
        c64[t] = 64 - 2 * (int)__popcll(wp[t]);
    }
    const float2 ib = ivbt[co];

    __syncthreads();

    uint64_t res = 0;
    for (int p = 0; p < 64; ++p) {
        const int inrow2 = (p >= 56 - o) ? 1 : 0;    // uniform
        const int w = o + p - (inrow2 ? 56 : 0);
        const int row = r0 + inrow2;
        const int rbase = inrow2 * 58;               // (rr-1)*58, rr = 1+inrow2

        int s = 0;
#pragma unroll
        for (int dr = 0; dr < 3; ++dr)
#pragma unroll
            for (int dc = 0; dc < 3; ++dc) {
                uint64_t a = tile[rbase + dr * 58 + w + dc];
                s += (int)__popcll(a ^ wp[dr * 3 + dc]);
            }
        int y = 576 - 2 * s;                         // zero-padded taps incl.

        unsigned um = 0;                             // invalid-tap mask (uniform)
        if (row == 0)  um |= 0x007u;
        if (row == 55) um |= 0x1C0u;
        if (w == 0)    um |= 0x049u;
        if (w == 55)   um |= 0x124u;
        if (um) {
#pragma unroll
            for (int t = 0; t < 9; ++t)
                if ((um >> t) & 1u) y -= c64[t];
        }

        float val = __fadd_rn(__fmul_rn((float)y, ib.x), ib.y);
        uint64_t word = __ballot(val >= 0.0f);
        res = (l == p) ? word : res;
    }

    size_t oidx = (size_t)wv * NPIX + (size_t)(b * HW_) + hw0 + l;
    if (MERGE) res |= Hin[oidx];
    Out[oidx] = res;
}

// ------------- K3: binary conv1x1 256->64 (planar bits -> bits) ------------
__global__ __launch_bounds__(256) void k3_conv1b(
    const uint64_t* __restrict__ H, const uint64_t* __restrict__ W12b,
    const float2* __restrict__ ivbt, uint64_t* __restrict__ A2)
{
    int p = blockIdx.x * 256 + threadIdx.x;   // < 50176
    uint64_t h0 = H[p];
    uint64_t h1 = H[NPIX + p];
    uint64_t h2 = H[2 * NPIX + p];
    uint64_t h3 = H[3 * NPIX + p];
    uint64_t bits = 0;
#pragma unroll 4
    for (int co = 0; co < 64; ++co) {
        const uint64_t* wp = W12b + co * 4;
        int s = (int)(__popcll(h0 ^ wp[0]) + __popcll(h1 ^ wp[1]) +
                      __popcll(h2 ^ wp[2]) + __popcll(h3 ^ wp[3]));
        int y = 256 - 2 * s;
        float2 ib = ivbt[co];
        float val = __fadd_rn(__fmul_rn((float)y, ib.x), ib.y);
        bits |= (uint64_t)(val >= 0.0f) << co;
    }
    A2[p] = bits;
}

// ------------- K4b: OR-pool 2x2 (planar S) + write +-1.0f ------------------
__global__ __launch_bounds__(256) void k4b_pool(
    const uint64_t* __restrict__ S, float* __restrict__ out)
{
    int o = blockIdx.x * 256 + threadIdx.x;   // < 16*256*28*28 = 3211264
    int ow = o % 28;
    int t = o / 28;
    int oh = t % 28; t /= 28;
    int co = t & 255;
    int b  = t >> 8;
    int k = co >> 6, j = co & 63;
    const uint64_t* Sk = S + (size_t)k * NPIX + (size_t)(b * HW_) + (2 * oh) * 56 + 2 * ow;
    uint64_t s = Sk[0] | Sk[1] | Sk[56] | Sk[57];
    out[o] = ((s >> j) & 1) ? 1.0f : -1.0f;
}

// ---------------------------------------------------------------------------
extern "C" void kernel_launch(void* const* d_in, const int* in_sizes, int n_in,
                              void* d_out, int out_size, void* d_ws, size_t ws_size,
                              hipStream_t stream)
{
    const float* x   = (const float*)d_in[0];
    const float* w11 = (const float*)d_in[1];
    const float* w31 = (const float*)d_in[2];
    const float* w12 = (const float*)d_in[3];
    const float* w32 = (const float*)d_in[4];
    const float* g11 = (const float*)d_in[5];
    const float* b11 = (const float*)d_in[6];
    const float* m11 = (const float*)d_in[7];
    const float* v11 = (const float*)d_in[8];
    const float* g31 = (const float*)d_in[9];
    const float* b31 = (const float*)d_in[10];
    const float* m31 = (const float*)d_in[11];
    const float* v31 = (const float*)d_in[12];
    const float* g12 = (const float*)d_in[13];
    const float* b12 = (const float*)d_in[14];
    const float* m12 = (const float*)d_in[15];
    const float* v12 = (const float*)d_in[16];
    const float* g32 = (const float*)d_in[17];
    const float* b32 = (const float*)d_in[18];
    const float* m32 = (const float*)d_in[19];
    const float* v32 = (const float*)d_in[20];

    char* ws = (char*)d_ws;
    uint64_t* W31b = (uint64_t*)(ws + OFF_W31B);
    uint64_t* W12b = (uint64_t*)(ws + OFF_W12B);
    uint64_t* W32b = (uint64_t*)(ws + OFF_W32B);
    float2* iv11 = (float2*)(ws + OFF_IV11);
    float2* iv31 = (float2*)(ws + OFF_IV31);
    float2* iv12 = (float2*)(ws + OFF_IV12);
    float2* iv32 = (float2*)(ws + OFF_IV32);
    float*  sgnT = (float*)(ws + OFF_SGNT);
    uint64_t* A1 = (uint64_t*)(ws + OFF_A1);
    uint64_t* A2 = (uint64_t*)(ws + OFF_A2);
    uint64_t* Hb = (uint64_t*)(ws + OFF_H);
    uint64_t* Sb = (uint64_t*)(ws + OFF_S);

    k0_prep<<<dim3(22), dim3(256), 0, stream>>>(
        w31, w12, w32,
        g11, b11, m11, v11, g31, b31, m31, v31,
        g12, b12, m12, v12, g32, b32, m32, v32,
        W31b, W12b, W32b, iv11, iv31, iv12, iv32);

    k0b_sgn<<<dim3(64), dim3(256), 0, stream>>>(w11, sgnT);

    k1_conv1<<<dim3(392), dim3(256), 0, stream>>>(x, sgnT, iv11, (uint32_t*)A1);

    k_conv3b<false><<<dim3(784), dim3(256), 0, stream>>>(A1, W31b, iv31, (const uint64_t*)nullptr, Hb);

    k3_conv1b<<<dim3(196), dim3(256), 0, stream>>>(Hb, W12b, iv12, A2);

    k_conv3b<true><<<dim3(784), dim3(256), 0, stream>>>(A2, W32b, iv32, Hb, Sb);

    k4b_pool<<<dim3(12544), dim3(256), 0, stream>>>(Sb, (float*)d_out);
}

// Round 8
// 139.601 us; speedup vs baseline: 1.9404x; 1.5183x over previous
//
#include <hip/hip_runtime.h>
#include <stdint.h>

#pragma clang fp contract(off)

// ---------------------------------------------------------------------------
// Binary ConvBlock, bit-exact to the fp32 numpy reference (validated r5-r7):
//   - stage 1: conv1x1(x, sgn w11): SEQUENTIAL fp32 chain over ci=0..255
//     ascending via fma(+-1.0f, x, acc) == fl(acc +- x). fp32 BN threshold.
//   - stages 2-4: exact-integer popcount convs, fp32 BN threshold:
//       inv = g/sqrt(v+1e-4f); beta = b - m*inv; val = y*inv + beta.
// k1: barrier-free, wave = 64px x 16ch, sign table via wave-uniform
// s_load_dwordx16 (group id through readfirstlane — r7 regression fix).
// conv3: ballot form (lane = co, weights in VGPRs, zero-padded LDS tile).
// H/S planar [quarter][px]. B=16, Cin=256, down=64, up=256, H=W=56.
// ---------------------------------------------------------------------------

#define HW_   3136          // 56*56
#define NPIX  50176         // 16*3136

// workspace layout (bytes)
#define OFF_W31B   0         // 2304 u64 ([co][tap])
#define OFF_W12B   18432     // 256 u64  ([co][k])
#define OFF_W32B   20480     // 2304 u64
#define OFF_IV11   38912     // 64 float2
#define OFF_IV31   39424     // 256 float2
#define OFF_IV12   41472     // 64 float2
#define OFF_IV32   41984     // 256 float2
#define OFF_SGNT   44032     // 16384 f32 (+-1.0f, [ci][j]) = 64 KiB
#define OFF_A1     109568    // 50176 u64 (bit j = ch j; u16 quarter per group)
#define OFF_A2     510976    // 50176 u64
#define OFF_H      912384    // 4 planes x 50176 u64 (bit = co within quarter)
#define OFF_S      2518016   // 4 planes x 50176 u64

__device__ inline float2 mk_ivbt(float g, float b, float m, float v) {
    float inv  = __fdiv_rn(g, __fsqrt_rn(__fadd_rn(v, 1e-4f)));
    float beta = __fsub_rn(b, __fmul_rn(m, inv));
    return make_float2(inv, beta);
}

// --------------------------- K0: pack weights ------------------------------
__global__ __launch_bounds__(256) void k0_prep(
    const float* __restrict__ w31, const float* __restrict__ w12,
    const float* __restrict__ w32,
    const float* __restrict__ g11, const float* __restrict__ b11,
    const float* __restrict__ m11, const float* __restrict__ v11,
    const float* __restrict__ g31, const float* __restrict__ b31,
    const float* __restrict__ m31, const float* __restrict__ v31,
    const float* __restrict__ g12, const float* __restrict__ b12,
    const float* __restrict__ m12, const float* __restrict__ v12,
    const float* __restrict__ g32, const float* __restrict__ b32,
    const float* __restrict__ m32, const float* __restrict__ v32,
    uint64_t* __restrict__ W31b, uint64_t* __restrict__ W12b,
    uint64_t* __restrict__ W32b,
    float2* __restrict__ iv11, float2* __restrict__ iv31,
    float2* __restrict__ iv12, float2* __restrict__ iv32)
{
    int t = blockIdx.x * 256 + threadIdx.x;
    if (t < 2304) {                      // W31b[co*9+tap]: bit ci
        int co = t / 9, tap = t % 9;
        uint64_t bits = 0;
        for (int ci = 0; ci < 64; ++ci)
            bits |= (uint64_t)(w31[(co * 64 + ci) * 9 + tap] >= 0.f) << ci;
        W31b[t] = bits;
    } else if (t < 2560) {               // W12b[co*4+k]: bit ci'
        int i = t - 2304, co = i >> 2, k = i & 3;
        uint64_t bits = 0;
        for (int ci = 0; ci < 64; ++ci)
            bits |= (uint64_t)(w12[co * 256 + k * 64 + ci] >= 0.f) << ci;
        W12b[i] = bits;
    } else if (t < 4864) {               // W32b
        int i = t - 2560, co = i / 9, tap = i % 9;
        uint64_t bits = 0;
        for (int ci = 0; ci < 64; ++ci)
            bits |= (uint64_t)(w32[(co * 64 + ci) * 9 + tap] >= 0.f) << ci;
        W32b[i] = bits;
    } else if (t < 5504) {               // BN (inv, beta) in fp32, np op order
        int i = t - 4864;
        if (i < 64)        iv11[i]       = mk_ivbt(g11[i],       b11[i],       m11[i],       v11[i]);
        else if (i < 320)  iv31[i - 64]  = mk_ivbt(g31[i - 64],  b31[i - 64],  m31[i - 64],  v31[i - 64]);
        else if (i < 384)  iv12[i - 320] = mk_ivbt(g12[i - 320], b12[i - 320], m12[i - 320], v12[i - 320]);
        else               iv32[i - 384] = mk_ivbt(g32[i - 384], b32[i - 384], m32[i - 384], v32[i - 384]);
    }
}

// ---------------- K0b: +-1.0f sign table, layout [ci][j] -------------------
__global__ __launch_bounds__(256) void k0b_sgn(
    const float* __restrict__ w11, float* __restrict__ sgnT)
{
    int t = blockIdx.x * 256 + threadIdx.x;   // < 16384; t = j*256 + ci
    int j = t >> 8, ci = t & 255;
    sgnT[ci * 64 + j] = (w11[t] >= 0.f) ? 1.0f : -1.0f;
}

// ------------- K1: fp32 SEQUENTIAL conv1x1 (x * sgn w11) + sign ------------
// grid 784, block 256 = 4 waves; wave = (px-chunk of 64, ch-group of 16).
// Barrier-free. lane = pixel (coalesced x). Sign floats via wave-uniform
// s_load_dwordx16 (group id made provably uniform with readfirstlane).
__global__ __launch_bounds__(256) void k1_conv1(
    const float* __restrict__ x, const float* __restrict__ sgnT,
    const float2* __restrict__ ivbt, unsigned short* __restrict__ A1)
{
    const int l = threadIdx.x & 63;
    const int g = __builtin_amdgcn_readfirstlane(threadIdx.x >> 6);  // 0..3
    const int chunk = blockIdx.x;            // 0..783
    const int b = chunk / 49;
    const int hw0 = (chunk % 49) * 64;
    const float* xp = x + (size_t)b * 256 * HW_ + hw0 + l;
    const float* sg = sgnT + g * 16;         // [ci][64] + g*16 (64B aligned)

    float acc[16];
#pragma unroll
    for (int j = 0; j < 16; ++j) acc[j] = 0.0f;

    for (int ci = 0; ci < 256; ci += 4) {    // ci ascending
        float xv0 = xp[(size_t)(ci + 0) * HW_];
        float xv1 = xp[(size_t)(ci + 1) * HW_];
        float xv2 = xp[(size_t)(ci + 2) * HW_];
        float xv3 = xp[(size_t)(ci + 3) * HW_];
        const float* s0 = sg + (ci + 0) * 64;
        const float* s1 = sg + (ci + 1) * 64;
        const float* s2 = sg + (ci + 2) * 64;
        const float* s3 = sg + (ci + 3) * 64;
#pragma unroll
        for (int j = 0; j < 16; ++j) acc[j] = __builtin_fmaf(s0[j], xv0, acc[j]);
#pragma unroll
        for (int j = 0; j < 16; ++j) acc[j] = __builtin_fmaf(s1[j], xv1, acc[j]);
#pragma unroll
        for (int j = 0; j < 16; ++j) acc[j] = __builtin_fmaf(s2[j], xv2, acc[j]);
#pragma unroll
        for (int j = 0; j < 16; ++j) acc[j] = __builtin_fmaf(s3[j], xv3, acc[j]);
    }

    unsigned bits = 0;
#pragma unroll
    for (int j = 0; j < 16; ++j) {
        float2 ib = ivbt[g * 16 + j];
        float val = __fadd_rn(__fmul_rn(acc[j], ib.x), ib.y);
        bits |= (val >= 0.0f) ? (1u << j) : 0u;
    }
    // u16 quarter g of the per-pixel u64 word (bit j_global = g*16 + j)
    A1[(size_t)(b * HW_ + hw0 + l) * 4 + g] = (unsigned short)bits;
}

// --------- conv3x3 ballot form: 64ch bits -> 256ch bits (planar out) -------
// grid 784, block 256 = 4 waves; wave = co-quarter, lane = co within quarter.
// Weights in VGPRs; taps from zero-padded LDS tile [4][58]; uniform px loop;
// output word assembled by __ballot (bit = lane = co). MERGE ORs Hin plane.
template <bool MERGE>
__global__ __launch_bounds__(256) void k_conv3b(
    const uint64_t* __restrict__ A, const uint64_t* __restrict__ Wb,
    const float2* __restrict__ ivbt, const uint64_t* __restrict__ Hin,
    uint64_t* __restrict__ Out)
{
    __shared__ uint64_t tile[4 * 58];
    const int l = threadIdx.x & 63;
    const int wv = threadIdx.x >> 6;
    const int chunk = blockIdx.x;            // 0..783
    const int b = chunk / 49;
    const int hw0 = (chunk % 49) * 64;
    const int r0 = hw0 / 56;
    const int o  = hw0 % 56;                 // 0..48 (chunk spans rows r0,r0+1)
    const int rfirst = r0 - 1;

    // stage zero-padded tile rows rfirst..rfirst+3, cols -1..56
    {
        int idx = threadIdx.x;
        if (idx < 4 * 58) {
            int rr = idx / 58, cc = idx % 58;
            int gh = rfirst + rr, gw = cc - 1;
            uint64_t v = 0;
            if ((unsigned)gh < 56u && (unsigned)gw < 56u)
                v = A[b * HW_ + gh * 56 + gw];
            tile[idx] = v;
        }
    }

    const int co = wv * 64 + l;
    uint64_t wp[9];
    int c64[9];
#pragma unroll
    for (int t = 0; t < 9; ++t) {
        wp[t] = Wb[co * 9 + t];
        c64[t] = 64 - 2 * (int)__popcll(wp[t]);
    }
    const float2 ib = ivbt[co];

    __syncthreads();

    uint64_t res = 0;
    for (int p = 0; p < 64; ++p) {
        const int inrow2 = (p >= 56 - o) ? 1 : 0;    // uniform
        const int w = o + p - (inrow2 ? 56 : 0);
        const int row = r0 + inrow2;
        const int rbase = inrow2 * 58;               // (rr-1)*58, rr = 1+inrow2

        int s = 0;
#pragma unroll
        for (int dr = 0; dr < 3; ++dr)
#pragma unroll
            for (int dc = 0; dc < 3; ++dc) {
                uint64_t a = tile[rbase + dr * 58 + w + dc];
                s += (int)__popcll(a ^ wp[dr * 3 + dc]);
            }
        int y = 576 - 2 * s;                         // zero-padded taps incl.

        unsigned um = 0;                             // invalid-tap mask (uniform)
        if (row == 0)  um |= 0x007u;
        if (row == 55) um |= 0x1C0u;
        if (w == 0)    um |= 0x049u;
        if (w == 55)   um |= 0x124u;
        if (um) {
#pragma unroll
            for (int t = 0; t < 9; ++t)
                if ((um >> t) & 1u) y -= c64[t];
        }

        float val = __fadd_rn(__fmul_rn((float)y, ib.x), ib.y);
        uint64_t word = __ballot(val >= 0.0f);
        res = (l == p) ? word : res;
    }

    size_t oidx = (size_t)wv * NPIX + (size_t)(b * HW_) + hw0 + l;
    if (MERGE) res |= Hin[oidx];
    Out[oidx] = res;
}

// ------------- K3: binary conv1x1 256->64 (planar bits -> bits) ------------
__global__ __launch_bounds__(256) void k3_conv1b(
    const uint64_t* __restrict__ H, const uint64_t* __restrict__ W12b,
    const float2* __restrict__ ivbt, uint64_t* __restrict__ A2)
{
    int p = blockIdx.x * 256 + threadIdx.x;   // < 50176
    uint64_t h0 = H[p];
    uint64_t h1 = H[NPIX + p];
    uint64_t h2 = H[2 * NPIX + p];
    uint64_t h3 = H[3 * NPIX + p];
    uint64_t bits = 0;
#pragma unroll 4
    for (int co = 0; co < 64; ++co) {
        const uint64_t* wp = W12b + co * 4;
        int s = (int)(__popcll(h0 ^ wp[0]) + __popcll(h1 ^ wp[1]) +
                      __popcll(h2 ^ wp[2]) + __popcll(h3 ^ wp[3]));
        int y = 256 - 2 * s;
        float2 ib = ivbt[co];
        float val = __fadd_rn(__fmul_rn((float)y, ib.x), ib.y);
        bits |= (uint64_t)(val >= 0.0f) << co;
    }
    A2[p] = bits;
}

// ------------- K4b: OR-pool 2x2 (planar S) + write +-1.0f ------------------
__global__ __launch_bounds__(256) void k4b_pool(
    const uint64_t* __restrict__ S, float* __restrict__ out)
{
    int o = blockIdx.x * 256 + threadIdx.x;   // < 16*256*28*28 = 3211264
    int ow = o % 28;
    int t = o / 28;
    int oh = t % 28; t /= 28;
    int co = t & 255;
    int b  = t >> 8;
    int k = co >> 6, j = co & 63;
    const uint64_t* Sk = S + (size_t)k * NPIX + (size_t)(b * HW_) + (2 * oh) * 56 + 2 * ow;
    uint64_t s = Sk[0] | Sk[1] | Sk[56] | Sk[57];
    out[o] = ((s >> j) & 1) ? 1.0f : -1.0f;
}

// ---------------------------------------------------------------------------
extern "C" void kernel_launch(void* const* d_in, const int* in_sizes, int n_in,
                              void* d_out, int out_size, void* d_ws, size_t ws_size,
                              hipStream_t stream)
{
    const float* x   = (const float*)d_in[0];
    const float* w11 = (const float*)d_in[1];
    const float* w31 = (const float*)d_in[2];
    const float* w12 = (const float*)d_in[3];
    const float* w32 = (const float*)d_in[4];
    const float* g11 = (const float*)d_in[5];
    const float* b11 = (const float*)d_in[6];
    const float* m11 = (const float*)d_in[7];
    const float* v11 = (const float*)d_in[8];
    const float* g31 = (const float*)d_in[9];
    const float* b31 = (const float*)d_in[10];
    const float* m31 = (const float*)d_in[11];
    const float* v31 = (const float*)d_in[12];
    const float* g12 = (const float*)d_in[13];
    const float* b12 = (const float*)d_in[14];
    const float* m12 = (const float*)d_in[15];
    const float* v12 = (const float*)d_in[16];
    const float* g32 = (const float*)d_in[17];
    const float* b32 = (const float*)d_in[18];
    const float* m32 = (const float*)d_in[19];
    const float* v32 = (const float*)d_in[20];

    char* ws = (char*)d_ws;
    uint64_t* W31b = (uint64_t*)(ws + OFF_W31B);
    uint64_t* W12b = (uint64_t*)(ws + OFF_W12B);
    uint64_t* W32b = (uint64_t*)(ws + OFF_W32B);
    float2* iv11 = (float2*)(ws + OFF_IV11);
    float2* iv31 = (float2*)(ws + OFF_IV31);
    float2* iv12 = (float2*)(ws + OFF_IV12);
    float2* iv32 = (float2*)(ws + OFF_IV32);
    float*  sgnT = (float*)(ws + OFF_SGNT);
    uint64_t* A1 = (uint64_t*)(ws + OFF_A1);
    uint64_t* A2 = (uint64_t*)(ws + OFF_A2);
    uint64_t* Hb = (uint64_t*)(ws + OFF_H);
    uint64_t* Sb = (uint64_t*)(ws + OFF_S);

    k0_prep<<<dim3(22), dim3(256), 0, stream>>>(
        w31, w12, w32,
        g11, b11, m11, v11, g31, b31, m31, v31,
        g12, b12, m12, v12, g32, b32, m32, v32,
        W31b, W12b, W32b, iv11, iv31, iv12, iv32);

    k0b_sgn<<<dim3(64), dim3(256), 0, stream>>>(w11, sgnT);

    k1_conv1<<<dim3(784), dim3(256), 0, stream>>>(x, sgnT, iv11, (unsigned short*)A1);

    k_conv3b<false><<<dim3(784), dim3(256), 0, stream>>>(A1, W31b, iv31, (const uint64_t*)nullptr, Hb);

    k3_conv1b<<<dim3(196), dim3(256), 0, stream>>>(Hb, W12b, iv12, A2);

    k_conv3b<true><<<dim3(784), dim3(256), 0, stream>>>(A2, W32b, iv32, Hb, Sb);

    k4b_pool<<<dim3(12544), dim3(256), 0, stream>>>(Sb, (float*)d_out);
}